// Round 16
// baseline (195.644 us; speedup 1.0000x reference)
//
#include <hip/hip_runtime.h>

// GPT2 attention w/ soft-threshold pruning — round 16.
// vs r15: (1) attn: defer-max REVERTED (r15 regression 62->70: the grow-branch
// forks the unrolled loop and kills pipelining); softthr kept. (2) gemm_qkv
// reformulated: Q split x split expressed as K-concat plain GEMM
// ([Ah|Al|Ah]@[Wh;Wh;Wl], K=3072, block-uniform offset wraps) -> uniform
// 2-buffer 32KB-LDS kernel, 5 blocks/CU (was 64KB/2 blocks + branches).
// (3) dispatches 10->7: prep = split_f32+wtrans(qkv)+wtrans(proj) fused;
// sv_partial folded into vtrans.

#define S_LEN 2048
#define DM    1024
#define NH    16
#define HD    64
#define SLOPE 10.0f
#define CMASK -10000.0f
#define SP    2080      // padded V^T row stride (shorts)

typedef short s16x4 __attribute__((ext_vector_type(4)));
typedef short s16x8 __attribute__((ext_vector_type(8)));
typedef float f32x4 __attribute__((ext_vector_type(4)));

#define MFMA16(a,b,c) __builtin_amdgcn_mfma_f32_16x16x32_bf16(a,b,c,0,0,0)
#define GLDS16(g,l) __builtin_amdgcn_global_load_lds( \
    (const __attribute__((address_space(1))) void*)(g), \
    (__attribute__((address_space(3))) void*)(l), 16, 0, 0)

__device__ __forceinline__ short f2bf(float f){
    unsigned u = __float_as_uint(f);
    u += 0x7fffu + ((u >> 16) & 1u);          // RNE
    return (short)(u >> 16);
}
__device__ __forceinline__ float bf2f(short x){
    return __uint_as_float(((unsigned)(unsigned short)x) << 16);
}
struct bfpair { short hi, lo; };
__device__ __forceinline__ bfpair split_bf(float x){
    bfpair r; r.hi = f2bf(x);
    r.lo = f2bf(x - bf2f(r.hi));
    return r;
}

// soft-threshold in cancellation-free form; s <= -1.5 rounds to exactly CMASK
// in numpy f32 too (sigma(10s) < 5e-8 -> C + eps == C).
__device__ __forceinline__ float softthr(float sv){
    float E = __expf(-SLOPE*sv);
    float w = sv - __fdividef((sv - CMASK)*E, 1.f + E);
    return (sv > -1.5f) ? w : CMASK;
}

// ---- staging: [ROWS][64] bf16 tile via global_load_lds, XOR-swizzled ----
template<int ROWS, int THREADS>
__device__ __forceinline__ void stage_tile(const short* gbase, int rstride,
                                           short* lds, int tid){
#pragma unroll
    for (int it = 0; it < ROWS*8/THREADS; ++it){
        int s = it*THREADS + tid;
        int row = s >> 3, grp = s & 7;
        const short* src = gbase + (size_t)row*rstride + ((grp ^ (row & 7)) << 3);
        GLDS16(src, lds + (size_t)s*8);
    }
}
__device__ __forceinline__ s16x8 frag(const short* lds, int row, int kg){
    return *(const s16x8*)&lds[row*64 + ((kg ^ (row & 7)) << 3)];
}

// ---------------- prep: split hs + transpose weights, one dispatch ----------
// bx <  2048: split hs -> Ahl[2048][2048] ([hi(1024) | lo(1024)] per row)
// 2048..2815: wtrans wqkv: n<1024 -> WqT[n][k]=hi, WqT[n][1024+k]=lo;
//             n>=1024 -> WkvT[n-1024][k]=hi
// 2816..3071: wtrans wprj -> WpT[n][k]=hi
__global__ __launch_bounds__(256)
void prep(const float* __restrict__ hs, const float* __restrict__ wqkv,
          const float* __restrict__ wprj, short* __restrict__ Ahl,
          short* __restrict__ WqT, short* __restrict__ WkvT,
          short* __restrict__ WpT)
{
    __shared__ float t[64][65];
    const int bx = blockIdx.x, tid = threadIdx.x;

    if (bx < 2048){
        int i = bx*256 + tid;                   // 0..524287
        int elem = i*4, row = elem >> 10, col = elem & 1023;
        float4 v = *(const float4*)&hs[(size_t)elem];
        bfpair a = split_bf(v.x), b = split_bf(v.y), c = split_bf(v.z), d = split_bf(v.w);
        s16x4 hv, lv;
        hv.x = a.hi; hv.y = b.hi; hv.z = c.hi; hv.w = d.hi;
        lv.x = a.lo; lv.y = b.lo; lv.z = c.lo; lv.w = d.lo;
        *(s16x4*)&Ahl[(size_t)row*2048 + col] = hv;
        *(s16x4*)&Ahl[(size_t)row*2048 + 1024 + col] = lv;
        return;
    }

    const float* W; int N, u;
    if (bx < 2816){ u = bx - 2048; W = wqkv; N = 3072; }
    else          { u = bx - 2816; W = wprj; N = 1024; }
    const int ntiles = N >> 6;
    const int tn = (u % ntiles)*64, tk = (u / ntiles)*64;

#pragma unroll
    for (int it = 0; it < 4; ++it){
        int idx = tid + it*256;
        int r = idx >> 4, c4 = (idx & 15)*4;
        float4 v = *(const float4*)&W[(size_t)(tk + r)*N + tn + c4];
        t[r][c4] = v.x; t[r][c4+1] = v.y; t[r][c4+2] = v.z; t[r][c4+3] = v.w;
    }
    __syncthreads();
#pragma unroll
    for (int it = 0; it < 4; ++it){
        int idx = tid + it*256;
        int n = idx >> 4, c4 = (idx & 15)*4;
        s16x4 hv, lv;
#pragma unroll
        for (int j = 0; j < 4; ++j){
            bfpair p = split_bf(t[c4+j][n]);
            hv[j] = p.hi; lv[j] = p.lo;
        }
        if (bx >= 2816){
            *(s16x4*)&WpT[(size_t)(tn + n)*1024 + tk + c4] = hv;
        } else if (tn < 1024){
            *(s16x4*)&WqT[(size_t)(tn + n)*2048 + tk + c4] = hv;
            *(s16x4*)&WqT[(size_t)(tn + n)*2048 + 1024 + tk + c4] = lv;
        } else {
            *(s16x4*)&WkvT[(size_t)(tn + n - 1024)*1024 + tk + c4] = hv;
        }
    }
}

// ---------- QKV GEMM: uniform plain GEMM, 32KB LDS, grid (24,16) ----------
// x%3: 0 = Q (K=3072 concat: Ah.Wh + Al.Wh + Ah.Wl), 1 = K, 2 = V (K=1024).
__global__ __launch_bounds__(256)
void gemm_qkv(const short* __restrict__ Ahl, const short* __restrict__ WqT,
              const short* __restrict__ WkvT, const float* __restrict__ bias,
              short* __restrict__ QHh, short* __restrict__ QHl,
              short* __restrict__ KH,  short* __restrict__ Vb)
{
    __shared__ __align__(16) short Ah_s[128*64];
    __shared__ __align__(16) short Bh_s[128*64];

    const int tid = threadIdx.x, lane = tid & 63, wid = tid >> 6;
    const int lr = lane & 15, lg = lane >> 4;
    const int brow = blockIdx.y*128;
    const int xs = blockIdx.x % 3, xi = blockIdx.x / 3;   // section, tile
    const int bcol = xs*1024 + xi*128;
    const bool isQ = (xs == 0);
    const int KTOT = isQ ? 3072 : 1024;
    const short* Bbase = isQ ? (WqT + (size_t)bcol*2048)
                             : (WkvT + (size_t)(bcol - 1024)*1024);
    const int bstride = isQ ? 2048 : 1024;
    const int wm = (wid >> 1)*64, wn = (wid & 1)*64;

    f32x4 acc[4][4];
#pragma unroll
    for (int m = 0; m < 4; ++m)
#pragma unroll
        for (int n = 0; n < 4; ++n) acc[m][n] = (f32x4){0.f,0.f,0.f,0.f};

    for (int k0 = 0; k0 < KTOT; k0 += 64){
        int acol  = (k0 < 2048) ? k0 : k0 - 2048;          // Ah,Al,Ah
        int bcolk = (isQ && k0 >= 1024) ? k0 - 1024 : k0;  // Wh,Wh,Wl
        stage_tile<128,256>(Ahl + (size_t)brow*2048 + acol, 2048, Ah_s, tid);
        stage_tile<128,256>(Bbase + bcolk, bstride, Bh_s, tid);
        __syncthreads();
#pragma unroll
        for (int kc = 0; kc < 2; ++kc){
            s16x8 ah[4], bh[4];
#pragma unroll
            for (int m = 0; m < 4; ++m)
                ah[m] = frag(Ah_s, wm + m*16 + lr, kc*4 + lg);
#pragma unroll
            for (int n = 0; n < 4; ++n)
                bh[n] = frag(Bh_s, wn + n*16 + lr, kc*4 + lg);
#pragma unroll
            for (int m = 0; m < 4; ++m)
#pragma unroll
                for (int n = 0; n < 4; ++n)
                    acc[m][n] = MFMA16(ah[m], bh[n], acc[m][n]);
        }
        __syncthreads();
    }

#pragma unroll
    for (int m = 0; m < 4; ++m)
#pragma unroll
        for (int n = 0; n < 4; ++n){
            int row  = brow + wm + m*16 + lg*4;
            int gcol = bcol + wn + n*16 + lr;
            float bv = bias[gcol];
            int col1 = gcol & 1023;
            int h0 = col1 >> 6, d = col1 & 63;
#pragma unroll
            for (int v = 0; v < 4; ++v){
                float val = acc[m][n][v] + bv;
                if (xs == 0){
                    bfpair p = split_bf(val);
                    size_t o = ((size_t)h0*S_LEN + row + v)*HD + d;
                    QHh[o] = p.hi; QHl[o] = p.lo;
                } else if (xs == 1){
                    KH[((size_t)h0*S_LEN + row + v)*HD + d] = f2bf(val);
                } else {
                    Vb[(size_t)(row + v)*DM + col1] = f2bf(val);
                }
            }
        }
}

// ---------------- proj GEMM: C = A@W^T + bias, f32 out ----------------
__global__ __launch_bounds__(256)
void gemm_proj(const short* __restrict__ Ahg, const short* __restrict__ Bhg,
               const float* __restrict__ bias, float* __restrict__ C)
{
    __shared__ __align__(16) short Ah_s[128*64];
    __shared__ __align__(16) short Bh_s[128*64];

    const int tid = threadIdx.x, lane = tid & 63, wid = tid >> 6;
    const int lr = lane & 15, lg = lane >> 4;
    const int brow = blockIdx.y*128, bcol = blockIdx.x*128;
    const int wm = (wid >> 1)*64, wn = (wid & 1)*64;

    f32x4 acc[4][4];
#pragma unroll
    for (int m = 0; m < 4; ++m)
#pragma unroll
        for (int n = 0; n < 4; ++n) acc[m][n] = (f32x4){0.f,0.f,0.f,0.f};

    for (int k0 = 0; k0 < DM; k0 += 64){
        stage_tile<128,256>(Ahg + (size_t)brow*DM + k0, DM, Ah_s, tid);
        stage_tile<128,256>(Bhg + (size_t)bcol*DM + k0, DM, Bh_s, tid);
        __syncthreads();
#pragma unroll
        for (int kc = 0; kc < 2; ++kc){
            s16x8 ah[4], bh[4];
#pragma unroll
            for (int m = 0; m < 4; ++m)
                ah[m] = frag(Ah_s, wm + m*16 + lr, kc*4 + lg);
#pragma unroll
            for (int n = 0; n < 4; ++n)
                bh[n] = frag(Bh_s, wn + n*16 + lr, kc*4 + lg);
#pragma unroll
            for (int m = 0; m < 4; ++m)
#pragma unroll
                for (int n = 0; n < 4; ++n)
                    acc[m][n] = MFMA16(ah[m], bh[n], acc[m][n]);
        }
        __syncthreads();
    }

#pragma unroll
    for (int m = 0; m < 4; ++m)
#pragma unroll
        for (int n = 0; n < 4; ++n){
            int row  = brow + wm + m*16 + lg*4;
            int gcol = bcol + wn + n*16 + lr;
            float bv = bias[gcol];
#pragma unroll
            for (int v = 0; v < 4; ++v)
                C[(size_t)(row + v)*DM + gcol] = acc[m][n][v] + bv;
        }
}

// ---- V [2048][1024] bf16 -> V^T [1024][SP] + per-(head,block) V sums ------
__global__ __launch_bounds__(256)
void vtrans(const short* __restrict__ Vb, short* __restrict__ Vt,
            float* __restrict__ PB)
{
    __shared__ short t[64][66];
    const int tid = threadIdx.x;
    const int h = blockIdx.x, b = blockIdx.y;
    const int td = h*64, ts = b*64;
#pragma unroll
    for (int it = 0; it < 4; ++it){
        int idx = tid + it*256;
        int r = idx >> 4, c4 = (idx & 15)*4;
        s16x4 v = *(const s16x4*)&Vb[(size_t)(ts + r)*DM + td + c4];
        t[r][c4] = v.x; t[r][c4+1] = v.y; t[r][c4+2] = v.z; t[r][c4+3] = v.w;
    }
    __syncthreads();
#pragma unroll
    for (int it = 0; it < 4; ++it){
        int idx = tid + it*256;
        int n = idx >> 4, c4 = (idx & 15)*4;
        s16x4 o;
#pragma unroll
        for (int j = 0; j < 4; ++j) o[j] = t[c4+j][n];
        *(s16x4*)&Vt[(size_t)(td + n)*SP + ts + c4] = o;
    }
    if (tid < 64){
        float s = 0.f;
#pragma unroll 8
        for (int r = 0; r < 64; ++r) s += bf2f(t[r][tid]);
        PB[((size_t)h*32 + b)*64 + tid] = s;
    }
}

__global__ __launch_bounds__(64)
void sv_suffix(const float* __restrict__ PB, float* __restrict__ SSV)
{
    int h = blockIdx.x, d = threadIdx.x;
    float s = 0.f;
    SSV[((size_t)h*33 + 32)*64 + d] = 0.f;
    for (int b = 31; b >= 0; --b){
        s += PB[((size_t)h*32 + b)*64 + d];
        SSV[((size_t)h*33 + b)*64 + d] = s;
    }
}

// -------- attn: 1280 blocks x 4 waves; block = (h, 64-row q-tile, <=8 kvb) --
__global__ __launch_bounds__(256)
void attn_fwd(const short* __restrict__ QHh, const short* __restrict__ QHl,
              const short* __restrict__ KH, const short* __restrict__ Vt,
              short* __restrict__ acc0, short* __restrict__ acc1,
              short* __restrict__ acc2, float* __restrict__ ML)
{
    __shared__ __align__(16) short kh_s[64*64];
    __shared__ __align__(16) short vt_s[64*64];
    __shared__ __align__(16) short Ps[4][16*72];

    const int j = blockIdx.x;                      // 0..1279
    const int h = (j & 7) + 8*((j >> 3) & 1);      // == j&15; XCD-pinned heads
    const int t = j >> 4;                          // 0..79
    int qst, c;
    if (t < 8)      { qst = t; c = 0; }
    else if (t < 24){ int u = t - 8;  qst = 8  + (u >> 1); c = u & 1; }
    else if (t < 48){ int u = t - 24; qst = 16 + u/3;      c = u - (u/3)*3; }
    else            { int u = t - 48; qst = 24 + (u >> 2); c = u & 3; }
    const int kv0 = c*8;
    const int kv1 = min(kv0 + 8, qst + 1);

    const int tid = threadIdx.x, lane = tid & 63, wid = tid >> 6;
    const int lr = lane & 15, lg = lane >> 4;
    const int qrow = qst*64 + wid*16 + lg*4;

    const short* qbh = QHh + ((size_t)h*S_LEN + qst*64 + wid*16)*HD;
    const short* qbl = QHl + ((size_t)h*S_LEN + qst*64 + wid*16)*HD;
    s16x8 aqh[2], aql[2];
#pragma unroll
    for (int kc = 0; kc < 2; ++kc){
        aqh[kc] = *(const s16x8*)&qbh[lr*HD + kc*32 + lg*8];
        aql[kc] = *(const s16x8*)&qbl[lr*HD + kc*32 + lg*8];
    }

    float m_run[4], l_run[4];
    f32x4 acc_o[4];
#pragma unroll
    for (int v = 0; v < 4; ++v){ m_run[v] = -1e30f; l_run[v] = 0.f; }
#pragma unroll
    for (int n = 0; n < 4; ++n) acc_o[n] = (f32x4){0.f,0.f,0.f,0.f};

    for (int kvb = kv0; kvb < kv1; ++kvb){
        __syncthreads();
        stage_tile<64,256>(KH + ((size_t)h*S_LEN + kvb*64)*HD, HD, kh_s, tid);
        stage_tile<64,256>(Vt + (size_t)(h*HD)*SP + kvb*64, SP, vt_s, tid);
        __syncthreads();

        // S = Q K^T (Q split hi/lo, K plain)
        f32x4 sc[4];
#pragma unroll
        for (int n = 0; n < 4; ++n) sc[n] = (f32x4){0.f,0.f,0.f,0.f};
#pragma unroll
        for (int kc = 0; kc < 2; ++kc)
#pragma unroll
            for (int n = 0; n < 4; ++n){
                s16x8 bkh = frag(kh_s, n*16 + lr, kc*4 + lg);
                sc[n] = MFMA16(aqh[kc], bkh, sc[n]);
                sc[n] = MFMA16(aql[kc], bkh, sc[n]);
            }

        // soft-threshold (+ causal mask only in diagonal block kvb==qst)
        float p[4][4], tmax[4];
#pragma unroll
        for (int v = 0; v < 4; ++v) tmax[v] = -1e30f;
        if (kvb == qst){
#pragma unroll
            for (int n = 0; n < 4; ++n){
                int key = kvb*64 + n*16 + lr;
#pragma unroll
                for (int v = 0; v < 4; ++v){
                    float w = (key > qrow + v) ? CMASK : softthr(sc[n][v]);
                    p[n][v] = w;
                    tmax[v] = fmaxf(tmax[v], w);
                }
            }
        } else {
#pragma unroll
            for (int n = 0; n < 4; ++n)
#pragma unroll
                for (int v = 0; v < 4; ++v){
                    float w = softthr(sc[n][v]);
                    p[n][v] = w;
                    tmax[v] = fmaxf(tmax[v], w);
                }
        }
#pragma unroll
        for (int v = 0; v < 4; ++v)
#pragma unroll
            for (int msk = 1; msk < 16; msk <<= 1)
                tmax[v] = fmaxf(tmax[v], __shfl_xor(tmax[v], msk, 64));

        float scale[4], rsum[4];
#pragma unroll
        for (int v = 0; v < 4; ++v){
            float mn = fmaxf(m_run[v], tmax[v]);
            scale[v] = __expf(m_run[v] - mn);
            m_run[v] = mn;
            rsum[v] = 0.f;
        }
#pragma unroll
        for (int n = 0; n < 4; ++n)
#pragma unroll
            for (int v = 0; v < 4; ++v){
                float e = __expf(p[n][v] - m_run[v]);
                p[n][v] = e;
                rsum[v] += e;
            }
#pragma unroll
        for (int v = 0; v < 4; ++v){
#pragma unroll
            for (int msk = 1; msk < 16; msk <<= 1)
                rsum[v] += __shfl_xor(rsum[v], msk, 64);
            l_run[v] = l_run[v]*scale[v] + rsum[v];
        }
#pragma unroll
        for (int n = 0; n < 4; ++n)
#pragma unroll
            for (int v = 0; v < 4; ++v) acc_o[n][v] *= scale[v];

        // P (D-layout) -> per-wave LDS -> A-frag layout
#pragma unroll
        for (int n = 0; n < 4; ++n)
#pragma unroll
            for (int v = 0; v < 4; ++v)
                Ps[wid][(lg*4 + v)*72 + 16*n + lr] = f2bf(p[n][v]);
        asm volatile("s_waitcnt lgkmcnt(0)" ::: "memory");

        s16x8 pa0 = *(const s16x8*)&Ps[wid][lr*72 + lg*8];
        s16x8 pa1 = *(const s16x8*)&Ps[wid][lr*72 + 32 + lg*8];
#pragma unroll
        for (int n = 0; n < 4; ++n){
            s16x8 bv0 = frag(vt_s, 16*n + lr, lg);      // keys 0..31
            s16x8 bv1 = frag(vt_s, 16*n + lr, 4 + lg);  // keys 32..63
            acc_o[n] = MFMA16(pa0, bv0, acc_o[n]);
            acc_o[n] = MFMA16(pa1, bv1, acc_o[n]);
        }
    }

    // store partial: 64 rows x 64 d bf16 + (m,l) f32 per row
    short* ab = (j < 512)  ? acc0 + (size_t)j*4096
              : (j < 1024) ? acc1 + (size_t)(j-512)*4096
                           : acc2 + (size_t)(j-1024)*4096;
#pragma unroll
    for (int n = 0; n < 4; ++n)
#pragma unroll
        for (int v = 0; v < 4; ++v)
            ab[(wid*16 + lg*4 + v)*64 + 16*n + lr] = f2bf(acc_o[n][v]);
    if (lr == 0){
#pragma unroll
        for (int v = 0; v < 4; ++v){
            ML[((size_t)j*64 + wid*16 + lg*4 + v)*2 + 0] = m_run[v];
            ML[((size_t)j*64 + wid*16 + lg*4 + v)*2 + 1] = l_run[v];
        }
    }
}

// ---------------- merge partials + analytic tail -> O bf16 [s][1024] --------
__global__ __launch_bounds__(256)
void attn_merge(const short* __restrict__ acc0, const short* __restrict__ acc1,
                const short* __restrict__ acc2, const float* __restrict__ ML,
                const float* __restrict__ SSV, short* __restrict__ O)
{
    const int b = blockIdx.x;          // 0..511
    const int h = b & 15, qst = b >> 4;
    const int d = threadIdx.x & 63, rg = threadIdx.x >> 6;
    const int C = (qst + 8) >> 3;
    const int tbase = (qst < 8)  ? qst
                    : (qst < 16) ? 8  + 2*(qst - 8)
                    : (qst < 24) ? 24 + 3*(qst - 16)
                                 : 48 + 4*(qst - 24);
    const float F = (float)(S_LEN - 64*(qst + 1));
    const float svd = SSV[((size_t)h*33 + (qst + 1))*64 + d];

    for (int i = 0; i < 16; ++i){
        int r = rg + 4*i;              // 0..63
        float M = -1e30f;
        for (int c = 0; c < C; ++c){
            int job = (tbase + c)*16 + h;
            M = fmaxf(M, ML[((size_t)job*64 + r)*2]);
        }
        float num = 0.f, den = 0.f;
        for (int c = 0; c < C; ++c){
            int job = (tbase + c)*16 + h;
            float m = ML[((size_t)job*64 + r)*2];
            float l = ML[((size_t)job*64 + r)*2 + 1];
            const short* ab = (job < 512)  ? acc0 + (size_t)job*4096
                            : (job < 1024) ? acc1 + (size_t)(job-512)*4096
                                           : acc2 + (size_t)(job-1024)*4096;
            float e = __expf(m - M);
            num += e * bf2f(ab[r*64 + d]);
            den += e * l;
        }
        float et = __expf(CMASK - M);
        num += et * svd;
        den += et * F;
        O[(size_t)(qst*64 + r)*DM + h*64 + d] = f2bf(num * __fdividef(1.f, den));
    }
}

extern "C" void kernel_launch(void* const* d_in, const int* in_sizes, int n_in,
                              void* d_out, int out_size, void* d_ws, size_t ws_size,
                              hipStream_t stream)
{
    (void)in_sizes; (void)n_in; (void)out_size; (void)ws_size;
    const float* hs   = (const float*)d_in[0];
    const float* wqkv = (const float*)d_in[1];
    const float* bqkv = (const float*)d_in[2];
    const float* wprj = (const float*)d_in[3];
    const float* bprj = (const float*)d_in[4];

    char* p = (char*)d_ws;                        // ~38.7 MiB used
    short* Ahl  = (short*)(p + (0ull  << 20));    // 8 MiB (-> O 0..4, accA 4..8)
    short* WqT  = (short*)(p + (8ull  << 20));    // 4 MiB (-> accB)
    short* WkvT = (short*)(p + (12ull << 20));    // 4 MiB (-> accC 12..14, ML 14..)
    short* WpT  = (short*)(p + (16ull << 20));    // 2 MiB (live to end)
    short* QHh  = (short*)(p + (18ull << 20));    // 4 MiB (head-major)
    short* QHl  = (short*)(p + (22ull << 20));    // 4 MiB
    short* KH   = (short*)(p + (26ull << 20));    // 4 MiB (head-major)
    short* Vbg  = (short*)(p + (30ull << 20));    // 4 MiB ([s][1024])
    short* VT   = (short*)(p + (34ull << 20));    // 4.07 MiB, ends ~38.07
    float* PB   = (float*)(p + (38ull << 20) + (256ull << 10));  // 128 KiB
    float* SSV  = (float*)(p + (38ull << 20) + (512ull << 10));  // 132 KiB
    short* O    = Ahl;                             // 0..4 MiB after attn
    short* accA = (short*)(p + (4ull  << 20));     // jobs 0..511
    short* accB = (short*)(p + (8ull  << 20));     // jobs 512..1023
    short* accC = (short*)(p + (12ull << 20));     // jobs 1024..1279
    float* ML   = (float*)(p + (14ull << 20));     // 640 KiB (old WkvT tail)

    prep<<<3072, 256, 0, stream>>>(hs, wqkv, wprj, Ahl, WqT, WkvT, WpT);

    gemm_qkv<<<dim3(24, 16), 256, 0, stream>>>(
        Ahl, WqT, WkvT, bqkv, QHh, QHl, KH, Vbg);

    vtrans<<<dim3(NH, S_LEN/64), 256, 0, stream>>>(Vbg, VT, PB);
    sv_suffix<<<NH, 64, 0, stream>>>(PB, SSV);

    attn_fwd<<<1280, 256, 0, stream>>>(QHh, QHl, KH, VT, accA, accB, accC, ML);
    attn_merge<<<512, 256, 0, stream>>>(accA, accB, accC, ML, SSV, O);

    gemm_proj<<<dim3(8, 16), 256, 0, stream>>>(O, WpT, bprj, (float*)d_out);
}

// Round 17
// 176.220 us; speedup vs baseline: 1.1102x; 1.1102x over previous
//
#include <hip/hip_runtime.h>

// GPT2 attention w/ soft-threshold pruning — round 17.
// vs r16: (1) gemm_qkv: BK=32 with 4-tile amortized staging (Ah/Al/Bh/Bl as
// 128x32 = 8KB tiles, 32KB total -> 5 blocks/CU; r16's K-concat tripled Q
// staging traffic AND r13's 64KB allowed only 2 blocks/CU so the per-iter
// vmcnt(0)+barrier drain was exposed). New 32-col swizzle grp^((row>>1)&3)
// = 2-way max bank alias (free). (2) attn inner softmax reverted to r13's
// exact sigmoid+IEEE form (measured 62us vs softthr's 66 — data beats the
// op-count theory). Everything else unchanged from r16.

#define S_LEN 2048
#define DM    1024
#define NH    16
#define HD    64
#define SLOPE 10.0f
#define CMASK -10000.0f
#define SP    2080      // padded V^T row stride (shorts)

typedef short s16x4 __attribute__((ext_vector_type(4)));
typedef short s16x8 __attribute__((ext_vector_type(8)));
typedef float f32x4 __attribute__((ext_vector_type(4)));

#define MFMA16(a,b,c) __builtin_amdgcn_mfma_f32_16x16x32_bf16(a,b,c,0,0,0)
#define GLDS16(g,l) __builtin_amdgcn_global_load_lds( \
    (const __attribute__((address_space(1))) void*)(g), \
    (__attribute__((address_space(3))) void*)(l), 16, 0, 0)

__device__ __forceinline__ short f2bf(float f){
    unsigned u = __float_as_uint(f);
    u += 0x7fffu + ((u >> 16) & 1u);          // RNE
    return (short)(u >> 16);
}
__device__ __forceinline__ float bf2f(short x){
    return __uint_as_float(((unsigned)(unsigned short)x) << 16);
}
struct bfpair { short hi, lo; };
__device__ __forceinline__ bfpair split_bf(float x){
    bfpair r; r.hi = f2bf(x);
    r.lo = f2bf(x - bf2f(r.hi));
    return r;
}

// ---- staging: [ROWS][64] bf16 tile via global_load_lds, XOR-swizzled ----
template<int ROWS, int THREADS>
__device__ __forceinline__ void stage_tile(const short* gbase, int rstride,
                                           short* lds, int tid){
#pragma unroll
    for (int it = 0; it < ROWS*8/THREADS; ++it){
        int s = it*THREADS + tid;
        int row = s >> 3, grp = s & 7;
        const short* src = gbase + (size_t)row*rstride + ((grp ^ (row & 7)) << 3);
        GLDS16(src, lds + (size_t)s*8);
    }
}
__device__ __forceinline__ s16x8 frag(const short* lds, int row, int kg){
    return *(const s16x8*)&lds[row*64 + ((kg ^ (row & 7)) << 3)];
}

// ---- staging: [ROWS][32] bf16 tile (BK=32), swizzle grp^((row>>1)&3) ----
template<int ROWS, int THREADS>
__device__ __forceinline__ void stage32(const short* gbase, int rstride,
                                        short* lds, int tid){
#pragma unroll
    for (int it = 0; it < ROWS*4/THREADS; ++it){
        int s = it*THREADS + tid;
        int row = s >> 2, grp = s & 3;
        const short* src = gbase + (size_t)row*rstride + ((grp ^ ((row >> 1) & 3)) << 3);
        GLDS16(src, lds + (size_t)s*8);
    }
}
__device__ __forceinline__ s16x8 frag32(const short* lds, int row, int kg){
    return *(const s16x8*)&lds[row*32 + ((kg ^ ((row >> 1) & 3)) << 3)];
}

// ---------------- prep: split hs + transpose weights, one dispatch ----------
__global__ __launch_bounds__(256)
void prep(const float* __restrict__ hs, const float* __restrict__ wqkv,
          const float* __restrict__ wprj, short* __restrict__ Ahl,
          short* __restrict__ WqT, short* __restrict__ WkvT,
          short* __restrict__ WpT)
{
    __shared__ float t[64][65];
    const int bx = blockIdx.x, tid = threadIdx.x;

    if (bx < 2048){
        int i = bx*256 + tid;
        int elem = i*4, row = elem >> 10, col = elem & 1023;
        float4 v = *(const float4*)&hs[(size_t)elem];
        bfpair a = split_bf(v.x), b = split_bf(v.y), c = split_bf(v.z), d = split_bf(v.w);
        s16x4 hv, lv;
        hv.x = a.hi; hv.y = b.hi; hv.z = c.hi; hv.w = d.hi;
        lv.x = a.lo; lv.y = b.lo; lv.z = c.lo; lv.w = d.lo;
        *(s16x4*)&Ahl[(size_t)row*2048 + col] = hv;
        *(s16x4*)&Ahl[(size_t)row*2048 + 1024 + col] = lv;
        return;
    }

    const float* W; int N, u;
    if (bx < 2816){ u = bx - 2048; W = wqkv; N = 3072; }
    else          { u = bx - 2816; W = wprj; N = 1024; }
    const int ntiles = N >> 6;
    const int tn = (u % ntiles)*64, tk = (u / ntiles)*64;

#pragma unroll
    for (int it = 0; it < 4; ++it){
        int idx = tid + it*256;
        int r = idx >> 4, c4 = (idx & 15)*4;
        float4 v = *(const float4*)&W[(size_t)(tk + r)*N + tn + c4];
        t[r][c4] = v.x; t[r][c4+1] = v.y; t[r][c4+2] = v.z; t[r][c4+3] = v.w;
    }
    __syncthreads();
#pragma unroll
    for (int it = 0; it < 4; ++it){
        int idx = tid + it*256;
        int n = idx >> 4, c4 = (idx & 15)*4;
        s16x4 hv, lv;
#pragma unroll
        for (int j = 0; j < 4; ++j){
            bfpair p = split_bf(t[c4+j][n]);
            hv[j] = p.hi; lv[j] = p.lo;
        }
        if (bx >= 2816){
            *(s16x4*)&WpT[(size_t)(tn + n)*1024 + tk + c4] = hv;
        } else if (tn < 1024){
            *(s16x4*)&WqT[(size_t)(tn + n)*2048 + tk + c4] = hv;
            *(s16x4*)&WqT[(size_t)(tn + n)*2048 + 1024 + tk + c4] = lv;
        } else {
            *(s16x4*)&WkvT[(size_t)(tn + n - 1024)*1024 + tk + c4] = hv;
        }
    }
}

// ---------- QKV GEMM: BK=32, 4-tile staging, 32KB LDS, grid (24,16) --------
// x%3: 0 = Q (Ah.Wh + Al.Wh + Ah.Wl, tiles Ah/Al/Bh/Bl), 1 = K, 2 = V.
__global__ __launch_bounds__(256)
void gemm_qkv(const short* __restrict__ Ahl, const short* __restrict__ WqT,
              const short* __restrict__ WkvT, const float* __restrict__ bias,
              short* __restrict__ QHh, short* __restrict__ QHl,
              short* __restrict__ KH,  short* __restrict__ Vb)
{
    __shared__ __align__(16) short LDS[4][128*32];

    const int tid = threadIdx.x, lane = tid & 63, wid = tid >> 6;
    const int lr = lane & 15, lg = lane >> 4;
    const int brow = blockIdx.y*128;
    const int xs = blockIdx.x % 3, xi = blockIdx.x / 3;
    const int bcol = xs*1024 + xi*128;
    const bool isQ = (xs == 0);
    const short* Abase = Ahl + (size_t)brow*2048;
    const short* Bbase = isQ ? (WqT + (size_t)(xi*128)*2048)
                             : (WkvT + (size_t)(bcol - 1024)*1024);
    const int bstr = isQ ? 2048 : 1024;
    const int wm = (wid >> 1)*64, wn = (wid & 1)*64;

    f32x4 acc[4][4];
#pragma unroll
    for (int m = 0; m < 4; ++m)
#pragma unroll
        for (int n = 0; n < 4; ++n) acc[m][n] = (f32x4){0.f,0.f,0.f,0.f};

    for (int k0 = 0; k0 < 1024; k0 += 32){
        stage32<128,256>(Abase + k0, 2048, LDS[0], tid);
        stage32<128,256>(Bbase + k0, bstr, LDS[2], tid);
        if (isQ){
            stage32<128,256>(Abase + 1024 + k0, 2048, LDS[1], tid);
            stage32<128,256>(Bbase + 1024 + k0, 2048, LDS[3], tid);
        }
        __syncthreads();
        s16x8 ah[4], al[4], bh[4], bl[4];
#pragma unroll
        for (int m = 0; m < 4; ++m)
            ah[m] = frag32(LDS[0], wm + m*16 + lr, lg);
#pragma unroll
        for (int n = 0; n < 4; ++n)
            bh[n] = frag32(LDS[2], wn + n*16 + lr, lg);
        if (isQ){
#pragma unroll
            for (int m = 0; m < 4; ++m)
                al[m] = frag32(LDS[1], wm + m*16 + lr, lg);
#pragma unroll
            for (int n = 0; n < 4; ++n)
                bl[n] = frag32(LDS[3], wn + n*16 + lr, lg);
        }
#pragma unroll
        for (int m = 0; m < 4; ++m)
#pragma unroll
            for (int n = 0; n < 4; ++n){
                acc[m][n] = MFMA16(ah[m], bh[n], acc[m][n]);
                if (isQ){
                    acc[m][n] = MFMA16(ah[m], bl[n], acc[m][n]);
                    acc[m][n] = MFMA16(al[m], bh[n], acc[m][n]);
                }
            }
        __syncthreads();
    }

#pragma unroll
    for (int m = 0; m < 4; ++m)
#pragma unroll
        for (int n = 0; n < 4; ++n){
            int row  = brow + wm + m*16 + lg*4;
            int gcol = bcol + wn + n*16 + lr;
            float bv = bias[gcol];
            int col1 = gcol & 1023;
            int h0 = col1 >> 6, d = col1 & 63;
#pragma unroll
            for (int v = 0; v < 4; ++v){
                float val = acc[m][n][v] + bv;
                if (xs == 0){
                    bfpair p = split_bf(val);
                    size_t o = ((size_t)h0*S_LEN + row + v)*HD + d;
                    QHh[o] = p.hi; QHl[o] = p.lo;
                } else if (xs == 1){
                    KH[((size_t)h0*S_LEN + row + v)*HD + d] = f2bf(val);
                } else {
                    Vb[(size_t)(row + v)*DM + col1] = f2bf(val);
                }
            }
        }
}

// ---------------- proj GEMM: C = A@W^T + bias, f32 out ----------------
__global__ __launch_bounds__(256)
void gemm_proj(const short* __restrict__ Ahg, const short* __restrict__ Bhg,
               const float* __restrict__ bias, float* __restrict__ C)
{
    __shared__ __align__(16) short Ah_s[128*64];
    __shared__ __align__(16) short Bh_s[128*64];

    const int tid = threadIdx.x, lane = tid & 63, wid = tid >> 6;
    const int lr = lane & 15, lg = lane >> 4;
    const int brow = blockIdx.y*128, bcol = blockIdx.x*128;
    const int wm = (wid >> 1)*64, wn = (wid & 1)*64;

    f32x4 acc[4][4];
#pragma unroll
    for (int m = 0; m < 4; ++m)
#pragma unroll
        for (int n = 0; n < 4; ++n) acc[m][n] = (f32x4){0.f,0.f,0.f,0.f};

    for (int k0 = 0; k0 < DM; k0 += 64){
        stage_tile<128,256>(Ahg + (size_t)brow*DM + k0, DM, Ah_s, tid);
        stage_tile<128,256>(Bhg + (size_t)bcol*DM + k0, DM, Bh_s, tid);
        __syncthreads();
#pragma unroll
        for (int kc = 0; kc < 2; ++kc){
            s16x8 ah[4], bh[4];
#pragma unroll
            for (int m = 0; m < 4; ++m)
                ah[m] = frag(Ah_s, wm + m*16 + lr, kc*4 + lg);
#pragma unroll
            for (int n = 0; n < 4; ++n)
                bh[n] = frag(Bh_s, wn + n*16 + lr, kc*4 + lg);
#pragma unroll
            for (int m = 0; m < 4; ++m)
#pragma unroll
                for (int n = 0; n < 4; ++n)
                    acc[m][n] = MFMA16(ah[m], bh[n], acc[m][n]);
        }
        __syncthreads();
    }

#pragma unroll
    for (int m = 0; m < 4; ++m)
#pragma unroll
        for (int n = 0; n < 4; ++n){
            int row  = brow + wm + m*16 + lg*4;
            int gcol = bcol + wn + n*16 + lr;
            float bv = bias[gcol];
#pragma unroll
            for (int v = 0; v < 4; ++v)
                C[(size_t)(row + v)*DM + gcol] = acc[m][n][v] + bv;
        }
}

// ---- V [2048][1024] bf16 -> V^T [1024][SP] + per-(head,block) V sums ------
__global__ __launch_bounds__(256)
void vtrans(const short* __restrict__ Vb, short* __restrict__ Vt,
            float* __restrict__ PB)
{
    __shared__ short t[64][66];
    const int tid = threadIdx.x;
    const int h = blockIdx.x, b = blockIdx.y;
    const int td = h*64, ts = b*64;
#pragma unroll
    for (int it = 0; it < 4; ++it){
        int idx = tid + it*256;
        int r = idx >> 4, c4 = (idx & 15)*4;
        s16x4 v = *(const s16x4*)&Vb[(size_t)(ts + r)*DM + td + c4];
        t[r][c4] = v.x; t[r][c4+1] = v.y; t[r][c4+2] = v.z; t[r][c4+3] = v.w;
    }
    __syncthreads();
#pragma unroll
    for (int it = 0; it < 4; ++it){
        int idx = tid + it*256;
        int n = idx >> 4, c4 = (idx & 15)*4;
        s16x4 o;
#pragma unroll
        for (int j = 0; j < 4; ++j) o[j] = t[c4+j][n];
        *(s16x4*)&Vt[(size_t)(td + n)*SP + ts + c4] = o;
    }
    if (tid < 64){
        float s = 0.f;
#pragma unroll 8
        for (int r = 0; r < 64; ++r) s += bf2f(t[r][tid]);
        PB[((size_t)h*32 + b)*64 + tid] = s;
    }
}

__global__ __launch_bounds__(64)
void sv_suffix(const float* __restrict__ PB, float* __restrict__ SSV)
{
    int h = blockIdx.x, d = threadIdx.x;
    float s = 0.f;
    SSV[((size_t)h*33 + 32)*64 + d] = 0.f;
    for (int b = 31; b >= 0; --b){
        s += PB[((size_t)h*32 + b)*64 + d];
        SSV[((size_t)h*33 + b)*64 + d] = s;
    }
}

// -------- attn: 1280 blocks x 4 waves; block = (h, 64-row q-tile, <=8 kvb) --
__global__ __launch_bounds__(256)
void attn_fwd(const short* __restrict__ QHh, const short* __restrict__ QHl,
              const short* __restrict__ KH, const short* __restrict__ Vt,
              short* __restrict__ acc0, short* __restrict__ acc1,
              short* __restrict__ acc2, float* __restrict__ ML)
{
    __shared__ __align__(16) short kh_s[64*64];
    __shared__ __align__(16) short vt_s[64*64];
    __shared__ __align__(16) short Ps[4][16*72];

    const int j = blockIdx.x;                      // 0..1279
    const int h = (j & 7) + 8*((j >> 3) & 1);      // == j&15; XCD-pinned heads
    const int t = j >> 4;                          // 0..79
    int qst, c;
    if (t < 8)      { qst = t; c = 0; }
    else if (t < 24){ int u = t - 8;  qst = 8  + (u >> 1); c = u & 1; }
    else if (t < 48){ int u = t - 24; qst = 16 + u/3;      c = u - (u/3)*3; }
    else            { int u = t - 48; qst = 24 + (u >> 2); c = u & 3; }
    const int kv0 = c*8;
    const int kv1 = min(kv0 + 8, qst + 1);

    const int tid = threadIdx.x, lane = tid & 63, wid = tid >> 6;
    const int lr = lane & 15, lg = lane >> 4;
    const int qrow = qst*64 + wid*16 + lg*4;

    const short* qbh = QHh + ((size_t)h*S_LEN + qst*64 + wid*16)*HD;
    const short* qbl = QHl + ((size_t)h*S_LEN + qst*64 + wid*16)*HD;
    s16x8 aqh[2], aql[2];
#pragma unroll
    for (int kc = 0; kc < 2; ++kc){
        aqh[kc] = *(const s16x8*)&qbh[lr*HD + kc*32 + lg*8];
        aql[kc] = *(const s16x8*)&qbl[lr*HD + kc*32 + lg*8];
    }

    float m_run[4], l_run[4];
    f32x4 acc_o[4];
#pragma unroll
    for (int v = 0; v < 4; ++v){ m_run[v] = -1e30f; l_run[v] = 0.f; }
#pragma unroll
    for (int n = 0; n < 4; ++n) acc_o[n] = (f32x4){0.f,0.f,0.f,0.f};

    for (int kvb = kv0; kvb < kv1; ++kvb){
        __syncthreads();
        stage_tile<64,256>(KH + ((size_t)h*S_LEN + kvb*64)*HD, HD, kh_s, tid);
        stage_tile<64,256>(Vt + (size_t)(h*HD)*SP + kvb*64, SP, vt_s, tid);
        __syncthreads();

        // S = Q K^T (Q split hi/lo, K plain)
        f32x4 sc[4];
#pragma unroll
        for (int n = 0; n < 4; ++n) sc[n] = (f32x4){0.f,0.f,0.f,0.f};
#pragma unroll
        for (int kc = 0; kc < 2; ++kc)
#pragma unroll
            for (int n = 0; n < 4; ++n){
                s16x8 bkh = frag(kh_s, n*16 + lr, kc*4 + lg);
                sc[n] = MFMA16(aqh[kc], bkh, sc[n]);
                sc[n] = MFMA16(aql[kc], bkh, sc[n]);
            }

        // soft-threshold (+ causal mask only in diagonal block kvb==qst)
        float p[4][4], tmax[4];
#pragma unroll
        for (int v = 0; v < 4; ++v) tmax[v] = -1e30f;
        if (kvb == qst){
#pragma unroll
            for (int n = 0; n < 4; ++n){
                int key = kvb*64 + n*16 + lr;
#pragma unroll
                for (int v = 0; v < 4; ++v){
                    float w;
                    if (key > qrow + v) w = CMASK;
                    else {
                        float sv = sc[n][v];
                        float sig = 1.f / (1.f + __expf(-SLOPE*sv));
                        w = CMASK + (sv - CMASK)*sig;
                    }
                    p[n][v] = w;
                    tmax[v] = fmaxf(tmax[v], w);
                }
            }
        } else {
#pragma unroll
            for (int n = 0; n < 4; ++n)
#pragma unroll
                for (int v = 0; v < 4; ++v){
                    float sv = sc[n][v];
                    float sig = 1.f / (1.f + __expf(-SLOPE*sv));
                    float w = CMASK + (sv - CMASK)*sig;
                    p[n][v] = w;
                    tmax[v] = fmaxf(tmax[v], w);
                }
        }
#pragma unroll
        for (int v = 0; v < 4; ++v)
#pragma unroll
            for (int msk = 1; msk < 16; msk <<= 1)
                tmax[v] = fmaxf(tmax[v], __shfl_xor(tmax[v], msk, 64));

        float scale[4], rsum[4];
#pragma unroll
        for (int v = 0; v < 4; ++v){
            float mn = fmaxf(m_run[v], tmax[v]);
            scale[v] = __expf(m_run[v] - mn);
            m_run[v] = mn;
            rsum[v] = 0.f;
        }
#pragma unroll
        for (int n = 0; n < 4; ++n)
#pragma unroll
            for (int v = 0; v < 4; ++v){
                float e = __expf(p[n][v] - m_run[v]);
                p[n][v] = e;
                rsum[v] += e;
            }
#pragma unroll
        for (int v = 0; v < 4; ++v){
#pragma unroll
            for (int msk = 1; msk < 16; msk <<= 1)
                rsum[v] += __shfl_xor(rsum[v], msk, 64);
            l_run[v] = l_run[v]*scale[v] + rsum[v];
        }
#pragma unroll
        for (int n = 0; n < 4; ++n)
#pragma unroll
            for (int v = 0; v < 4; ++v) acc_o[n][v] *= scale[v];

        // P (D-layout) -> per-wave LDS -> A-frag layout
#pragma unroll
        for (int n = 0; n < 4; ++n)
#pragma unroll
            for (int v = 0; v < 4; ++v)
                Ps[wid][(lg*4 + v)*72 + 16*n + lr] = f2bf(p[n][v]);
        asm volatile("s_waitcnt lgkmcnt(0)" ::: "memory");

        s16x8 pa0 = *(const s16x8*)&Ps[wid][lr*72 + lg*8];
        s16x8 pa1 = *(const s16x8*)&Ps[wid][lr*72 + 32 + lg*8];
#pragma unroll
        for (int n = 0; n < 4; ++n){
            s16x8 bv0 = frag(vt_s, 16*n + lr, lg);      // keys 0..31
            s16x8 bv1 = frag(vt_s, 16*n + lr, 4 + lg);  // keys 32..63
            acc_o[n] = MFMA16(pa0, bv0, acc_o[n]);
            acc_o[n] = MFMA16(pa1, bv1, acc_o[n]);
        }
    }

    // store partial: 64 rows x 64 d bf16 + (m,l) f32 per row
    short* ab = (j < 512)  ? acc0 + (size_t)j*4096
              : (j < 1024) ? acc1 + (size_t)(j-512)*4096
                           : acc2 + (size_t)(j-1024)*4096;
#pragma unroll
    for (int n = 0; n < 4; ++n)
#pragma unroll
        for (int v = 0; v < 4; ++v)
            ab[(wid*16 + lg*4 + v)*64 + 16*n + lr] = f2bf(acc_o[n][v]);
    if (lr == 0){
#pragma unroll
        for (int v = 0; v < 4; ++v){
            ML[((size_t)j*64 + wid*16 + lg*4 + v)*2 + 0] = m_run[v];
            ML[((size_t)j*64 + wid*16 + lg*4 + v)*2 + 1] = l_run[v];
        }
    }
}

// ---------------- merge partials + analytic tail -> O bf16 [s][1024] --------
__global__ __launch_bounds__(256)
void attn_merge(const short* __restrict__ acc0, const short* __restrict__ acc1,
                const short* __restrict__ acc2, const float* __restrict__ ML,
                const float* __restrict__ SSV, short* __restrict__ O)
{
    const int b = blockIdx.x;          // 0..511
    const int h = b & 15, qst = b >> 4;
    const int d = threadIdx.x & 63, rg = threadIdx.x >> 6;
    const int C = (qst + 8) >> 3;
    const int tbase = (qst < 8)  ? qst
                    : (qst < 16) ? 8  + 2*(qst - 8)
                    : (qst < 24) ? 24 + 3*(qst - 16)
                                 : 48 + 4*(qst - 24);
    const float F = (float)(S_LEN - 64*(qst + 1));
    const float svd = SSV[((size_t)h*33 + (qst + 1))*64 + d];

    for (int i = 0; i < 16; ++i){
        int r = rg + 4*i;              // 0..63
        float M = -1e30f;
        for (int c = 0; c < C; ++c){
            int job = (tbase + c)*16 + h;
            M = fmaxf(M, ML[((size_t)job*64 + r)*2]);
        }
        float num = 0.f, den = 0.f;
        for (int c = 0; c < C; ++c){
            int job = (tbase + c)*16 + h;
            float m = ML[((size_t)job*64 + r)*2];
            float l = ML[((size_t)job*64 + r)*2 + 1];
            const short* ab = (job < 512)  ? acc0 + (size_t)job*4096
                            : (job < 1024) ? acc1 + (size_t)(job-512)*4096
                                           : acc2 + (size_t)(job-1024)*4096;
            float e = __expf(m - M);
            num += e * bf2f(ab[r*64 + d]);
            den += e * l;
        }
        float et = __expf(CMASK - M);
        num += et * svd;
        den += et * F;
        O[(size_t)(qst*64 + r)*DM + h*64 + d] = f2bf(num * __fdividef(1.f, den));
    }
}

extern "C" void kernel_launch(void* const* d_in, const int* in_sizes, int n_in,
                              void* d_out, int out_size, void* d_ws, size_t ws_size,
                              hipStream_t stream)
{
    (void)in_sizes; (void)n_in; (void)out_size; (void)ws_size;
    const float* hs   = (const float*)d_in[0];
    const float* wqkv = (const float*)d_in[1];
    const float* bqkv = (const float*)d_in[2];
    const float* wprj = (const float*)d_in[3];
    const float* bprj = (const float*)d_in[4];

    char* p = (char*)d_ws;                        // ~38.7 MiB used
    short* Ahl  = (short*)(p + (0ull  << 20));    // 8 MiB (-> O 0..4, accA 4..8)
    short* WqT  = (short*)(p + (8ull  << 20));    // 4 MiB (-> accB)
    short* WkvT = (short*)(p + (12ull << 20));    // 4 MiB (-> accC 12..14, ML 14..)
    short* WpT  = (short*)(p + (16ull << 20));    // 2 MiB (live to end)
    short* QHh  = (short*)(p + (18ull << 20));    // 4 MiB (head-major)
    short* QHl  = (short*)(p + (22ull << 20));    // 4 MiB
    short* KH   = (short*)(p + (26ull << 20));    // 4 MiB (head-major)
    short* Vbg  = (short*)(p + (30ull << 20));    // 4 MiB ([s][1024])
    short* VT   = (short*)(p + (34ull << 20));    // 4.07 MiB, ends ~38.07
    float* PB   = (float*)(p + (38ull << 20) + (256ull << 10));  // 128 KiB
    float* SSV  = (float*)(p + (38ull << 20) + (512ull << 10));  // 132 KiB
    short* O    = Ahl;                             // 0..4 MiB after attn
    short* accA = (short*)(p + (4ull  << 20));     // jobs 0..511
    short* accB = (short*)(p + (8ull  << 20));     // jobs 512..1023
    short* accC = (short*)(p + (12ull << 20));     // jobs 1024..1279
    float* ML   = (float*)(p + (14ull << 20));     // 640 KiB (old WkvT tail)

    prep<<<3072, 256, 0, stream>>>(hs, wqkv, wprj, Ahl, WqT, WkvT, WpT);

    gemm_qkv<<<dim3(24, 16), 256, 0, stream>>>(
        Ahl, WqT, WkvT, bqkv, QHh, QHl, KH, Vbg);

    vtrans<<<dim3(NH, S_LEN/64), 256, 0, stream>>>(Vbg, VT, PB);
    sv_suffix<<<NH, 64, 0, stream>>>(PB, SSV);

    attn_fwd<<<1280, 256, 0, stream>>>(QHh, QHl, KH, VT, accA, accB, accC, ML);
    attn_merge<<<512, 256, 0, stream>>>(accA, accB, accC, ML, SSV, O);

    gemm_proj<<<dim3(8, 16), 256, 0, stream>>>(O, WpT, bprj, (float*)d_out);
}